// Round 15
// baseline (1193.655 us; speedup 1.0000x reference)
//
#include <hip/hip_runtime.h>
#include <hip/hip_fp16.h>

#define DD 64
#define NUM_GRAPHS 64
#define AGG_BLOCKS 2048
#define EB 512          // edge-blocks for hist/scatter passes
#define BINW 256        // nodes per bin (target-sorted build)
#define BINW2 128       // nodes per bin (source-sorted push build)
#define MAXNB 512
#define MAXNB2 1024
#define EBIN_CAP 6144

typedef _Float16 h2_t __attribute__((ext_vector_type(2)));

__device__ __forceinline__ float fdot2u(unsigned a, unsigned b, float c) {
    return __builtin_amdgcn_fdot2(__builtin_bit_cast(h2_t, a),
                                  __builtin_bit_cast(h2_t, b), c, false);
}

// ---- pass A: per-edge-block histogram over target bins ----
__global__ __launch_bounds__(256) void k_hist(const int* __restrict__ col,
                                              int* __restrict__ H, int E, int NB, int CE) {
    __shared__ int h[MAXNB];
    int eb = blockIdx.x, t = threadIdx.x;
    for (int i = t; i < NB; i += 256) h[i] = 0;
    __syncthreads();
    int e0 = eb * CE, e1 = min(E, e0 + CE);
    for (int e = e0 + t; e < e1; e += 256) atomicAdd(&h[col[e] >> 8], 1);
    __syncthreads();
    for (int i = t; i < NB; i += 256) H[eb * NB + i] = h[i];
}

// ---- histogram over SOURCE bins (BINW2=128) ----
__global__ __launch_bounds__(256) void k_hist2(const int* __restrict__ row,
                                               int* __restrict__ H, int E, int NB, int CE) {
    __shared__ int h[MAXNB2];
    int eb = blockIdx.x, t = threadIdx.x;
    for (int i = t; i < NB; i += 256) h[i] = 0;
    __syncthreads();
    int e0 = eb * CE, e1 = min(E, e0 + CE);
    for (int e = e0 + t; e < e1; e += 256) atomicAdd(&h[row[e] >> 7], 1);
    __syncthreads();
    for (int i = t; i < NB; i += 256) H[eb * NB + i] = h[i];
}

// ---- per-bin exclusive scan over the EB edge-blocks (works for any NB) ----
__global__ __launch_bounds__(256) void k_scanA(int* __restrict__ H,
                                               int* __restrict__ bintot, int NB) {
    __shared__ int s[256];
    int b = blockIdx.x, t = threadIdx.x;
    int i0 = (2 * t) * NB + b, i1 = (2 * t + 1) * NB + b;
    int v0 = H[i0], v1 = H[i1];
    int tot = v0 + v1;
    s[t] = tot;
    __syncthreads();
    for (int off = 1; off < 256; off <<= 1) {
        int tv = (t >= off) ? s[t - off] : 0;
        __syncthreads();
        s[t] += tv;
        __syncthreads();
    }
    int excl = s[t] - tot;
    H[i0] = excl;
    H[i1] = excl + v0;
    if (t == 255) bintot[b] = s[255];
}

// ---- scan bin totals (≤512 bins) ----
__global__ void k_scanB(const int* __restrict__ bintot, int* __restrict__ binstart, int NB) {
    __shared__ int s[512];
    int t = threadIdx.x;
    int v = (t < NB) ? bintot[t] : 0;
    s[t] = v;
    __syncthreads();
    for (int off = 1; off < 512; off <<= 1) {
        int tv = (t >= off) ? s[t - off] : 0;
        __syncthreads();
        s[t] += tv;
        __syncthreads();
    }
    if (t < NB) binstart[t] = s[t] - v;
    if (t == 511) binstart[NB] = s[511];
}

// ---- scan bin totals (≤1024 bins, 1024 threads) ----
__global__ void k_scanB2(const int* __restrict__ bintot, int* __restrict__ binstart, int NB) {
    __shared__ int s[1024];
    int t = threadIdx.x;
    int v = (t < NB) ? bintot[t] : 0;
    s[t] = v;
    __syncthreads();
    for (int off = 1; off < 1024; off <<= 1) {
        int tv = (t >= off) ? s[t - off] : 0;
        __syncthreads();
        s[t] += tv;
        __syncthreads();
    }
    if (t < NB) binstart[t] = s[t] - v;
    if (t == 1023) binstart[NB] = s[1023];
}

// ---- scatter packed edges into target-bin regions ----
__global__ __launch_bounds__(256) void k_scatbin(const int* __restrict__ row,
                                                 const int* __restrict__ col,
                                                 const int* __restrict__ H,
                                                 const int* __restrict__ binstart,
                                                 unsigned* __restrict__ binned,
                                                 int E, int NB, int CE) {
    __shared__ int off[MAXNB];
    int eb = blockIdx.x, t = threadIdx.x;
    for (int i = t; i < NB; i += 256) off[i] = binstart[i] + H[eb * NB + i];
    __syncthreads();
    int e0 = eb * CE, e1 = min(E, e0 + CE);
    for (int e = e0 + t; e < e1; e += 256) {
        int c = col[e], r = row[e];
        int slot = atomicAdd(&off[c >> 8], 1);
        binned[slot] = ((unsigned)(c & 255) << 24) | (unsigned)r;
    }
}

// ---- scatter push payloads into SOURCE-bin regions:
//      payload = (localrow<<24) | qpk[col]   (qpk = batch<<18 | half(dinv)) ----
__global__ __launch_bounds__(256) void k_scatbin2(const int* __restrict__ row,
                                                  const int* __restrict__ col,
                                                  const int* __restrict__ H,
                                                  const int* __restrict__ binstart,
                                                  const unsigned* __restrict__ qpk,
                                                  unsigned* __restrict__ binned,
                                                  int E, int NB, int CE) {
    __shared__ int off[MAXNB2];
    int eb = blockIdx.x, t = threadIdx.x;
    for (int i = t; i < NB; i += 256) off[i] = binstart[i] + H[eb * NB + i];
    __syncthreads();
    int e0 = eb * CE, e1 = min(E, e0 + CE);
    for (int e = e0 + t; e < e1; e += 256) {
        int r = row[e], c = col[e];
        int slot = atomicAdd(&off[r >> 7], 1);
        binned[slot] = ((unsigned)(r & 127) << 24) | qpk[c];
    }
}

// ---- per-bin CSR finalize in LDS; also emits qpk ----
__global__ __launch_bounds__(256) void k_bincsr(const unsigned* __restrict__ binned,
                                                const int* __restrict__ binstart,
                                                const int* __restrict__ nt,
                                                const int* __restrict__ batch,
                                                int* __restrict__ srcidx,
                                                int* __restrict__ rowptr,
                                                float* __restrict__ dinv,
                                                int2* __restrict__ pk,
                                                unsigned* __restrict__ qpk, int N, int NB) {
    __shared__ unsigned arr[EBIN_CAP];
    __shared__ int sorted_[EBIN_CAP];
    __shared__ int cnt[BINW];
    __shared__ int base[BINW];
    __shared__ int cursor[BINW];
    int b = blockIdx.x, t = threadIdx.x;
    int s0 = binstart[b], s1 = binstart[b + 1];
    int binsz = s1 - s0;
    if (binsz > EBIN_CAP) binsz = EBIN_CAP;
    cnt[t] = 0;
    for (int i = t; i < binsz; i += 256) arr[i] = binned[s0 + i];
    __syncthreads();
    for (int i = t; i < binsz; i += 256) atomicAdd(&cnt[arr[i] >> 24], 1);
    __syncthreads();
    int v = cnt[t];
    base[t] = v;
    __syncthreads();
    for (int off = 1; off < 256; off <<= 1) {
        int tv = (t >= off) ? base[t - off] : 0;
        __syncthreads();
        base[t] += tv;
        __syncthreads();
    }
    int excl = base[t] - v;
    __syncthreads();
    base[t] = excl;
    cursor[t] = excl;
    __syncthreads();
    for (int i = t; i < binsz; i += 256) {
        unsigned val = arr[i];
        int pos = atomicAdd(&cursor[val >> 24], 1);
        sorted_[pos] = (int)(val & 0xFFFFFF);
    }
    __syncthreads();
    for (int i = t; i < binsz; i += 256) srcidx[s0 + i] = sorted_[i];
    int node = b * BINW + t;
    if (node < N) {
        rowptr[node] = s0 + base[t];
        float di = rsqrtf((float)cnt[t] + 1.0f);   // +1 = self loop
        dinv[node] = di;
        pk[node] = make_int2(nt[node], __float_as_int(di));
        qpk[node] = ((unsigned)batch[node] << 18) |
                    (unsigned)__half_as_ushort(__float2half(di));
    }
    if (b == NB - 1 && t == 0) rowptr[N] = s1;
}

// ---- per-edge packed operand in CSR order ----
__global__ void k_buildepk(const int* __restrict__ srcidx, const int2* __restrict__ pk,
                           unsigned* __restrict__ epku, int E) {
    int i = blockIdx.x * blockDim.x + threadIdx.x;
    if (i >= E) return;
    int2 p = pk[srcidx[i]];
    epku[i] = ((unsigned)p.x << 16) |
              (unsigned)__half_as_ushort(__float2half(__int_as_float(p.y)));
}

// ---- embW1 = emb_table @ W1 ----
__global__ void k_embW1(const float* __restrict__ emb, const float* __restrict__ W1,
                        float* __restrict__ embW1, int V) {
    __shared__ float er[DD];
    int v = blockIdx.x, j = threadIdx.x;
    er[j] = emb[v * DD + j];
    __syncthreads();
    float acc = 0.0f;
    #pragma unroll
    for (int d = 0; d < DD; ++d) acc += er[d] * W1[d * DD + j];
    embW1[v * DD + j] = acc;
}

// ---- pack W into half2 pairs ----
__global__ void k_packW(const float* __restrict__ W, unsigned* __restrict__ Wpk) {
    int t = blockIdx.x * blockDim.x + threadIdx.x;
    if (t >= 32 * DD) return;
    int p = t >> 6, j = t & 63;
    __half2 h = __floats2half2_rn(W[(2 * p) * DD + j], W[(2 * p + 1) * DD + j]);
    Wpk[t] = __builtin_bit_cast(unsigned, h);
}

// epilogue dot, v distributed 4 features/lane
__device__ __forceinline__ float epi_dot_q(float4 v, const unsigned* Wc) {
    __half2 h0 = __floats2half2_rn(v.x, v.y);
    __half2 h1 = __floats2half2_rn(v.z, v.w);
    int vp0 = __builtin_bit_cast(int, h0);
    int vp1 = __builtin_bit_cast(int, h1);
    float o0 = 0.f, o1 = 0.f, o2 = 0.f, o3 = 0.f;
    #pragma unroll
    for (int p = 0; p < 32; p += 4) {
        o0 = fdot2u((unsigned)__builtin_amdgcn_readlane(vp0, (p + 0) >> 1), Wc[p + 0], o0);
        o1 = fdot2u((unsigned)__builtin_amdgcn_readlane(vp1, (p + 1) >> 1), Wc[p + 1], o1);
        o2 = fdot2u((unsigned)__builtin_amdgcn_readlane(vp0, (p + 2) >> 1), Wc[p + 2], o2);
        o3 = fdot2u((unsigned)__builtin_amdgcn_readlane(vp1, (p + 3) >> 1), Wc[p + 3], o3);
    }
    return (o0 + o1) + (o2 + o3);
}

__device__ __forceinline__ void acc_h4(float4& a, uint2 r) {
    float2 f0 = __half22float2(*(const __half2*)&r.x);
    float2 f1 = __half22float2(*(const __half2*)&r.y);
    a.x += f0.x; a.y += f0.y; a.z += f1.x; a.w += f1.y;
}

// quarter-wave gather, 2-stage software pipeline
__device__ __forceinline__ float4 gather_sum_q(const int* __restrict__ srcidx,
                                               const __half* __restrict__ Hs,
                                               int s, int e, int g, int l) {
    float4 A = {0,0,0,0}, B = {0,0,0,0}, C = {0,0,0,0}, D = {0,0,0,0};
    int k = s;
    int kend = s + ((e - s) & ~15);
    if (k < kend) {
        uint2 r0 = *(const uint2*)(Hs + (long)srcidx[k + g] * DD + 4 * l);
        uint2 r1 = *(const uint2*)(Hs + (long)srcidx[k + 4 + g] * DD + 4 * l);
        uint2 r2 = *(const uint2*)(Hs + (long)srcidx[k + 8 + g] * DD + 4 * l);
        uint2 r3 = *(const uint2*)(Hs + (long)srcidx[k + 12 + g] * DD + 4 * l);
        k += 16;
        for (; k < kend; k += 16) {
            uint2 n0 = *(const uint2*)(Hs + (long)srcidx[k + g] * DD + 4 * l);
            uint2 n1 = *(const uint2*)(Hs + (long)srcidx[k + 4 + g] * DD + 4 * l);
            uint2 n2 = *(const uint2*)(Hs + (long)srcidx[k + 8 + g] * DD + 4 * l);
            uint2 n3 = *(const uint2*)(Hs + (long)srcidx[k + 12 + g] * DD + 4 * l);
            acc_h4(A, r0); acc_h4(B, r1); acc_h4(C, r2); acc_h4(D, r3);
            r0 = n0; r1 = n1; r2 = n2; r3 = n3;
        }
        acc_h4(A, r0); acc_h4(B, r1); acc_h4(C, r2); acc_h4(D, r3);
    }
    for (; k < e; k += 4) {
        if (k + g < e) {
            uint2 rr = *(const uint2*)(Hs + (long)srcidx[k + g] * DD + 4 * l);
            acc_h4(A, rr);
        }
    }
    A.x += B.x + C.x + D.x; A.y += B.y + C.y + D.y;
    A.z += B.z + C.z + D.z; A.w += B.w + C.w + D.w;
    A.x += __shfl_xor(A.x, 16, 64); A.x += __shfl_xor(A.x, 32, 64);
    A.y += __shfl_xor(A.y, 16, 64); A.y += __shfl_xor(A.y, 32, 64);
    A.z += __shfl_xor(A.z, 16, 64); A.z += __shfl_xor(A.z, 32, 64);
    A.w += __shfl_xor(A.w, 16, 64); A.w += __shfl_xor(A.w, 32, 64);
    return A;
}

// ---- layer-1, quarter-wave (LDS ew table; no matmul) ----
__global__ __launch_bounds__(256, 4) void k_agg1_fused(const int* __restrict__ rowptr,
                                                    const unsigned* __restrict__ epku,
                                                    const int2* __restrict__ pk,
                                                    const float* __restrict__ embW1,
                                                    const float* __restrict__ b1,
                                                    __half* __restrict__ OUT, int N, int V) {
    __shared__ float ew[30 * DD];
    int tid = threadIdx.x;
    for (int k = tid; k < V * DD; k += 256) ew[k] = embW1[k];
    __syncthreads();
    int lane = tid & 63;
    int g = lane >> 4, l = lane & 15;
    float4 bq = *(const float4*)(b1 + 4 * l);
    int wave0 = blockIdx.x * 4 + (tid >> 6);
    int wstride = gridDim.x * 4;
    for (int node = __builtin_amdgcn_readfirstlane(wave0); node < N;
         node += wstride) {
        int s = rowptr[node], e = rowptr[node + 1];
        float4 acc = {0.f, 0.f, 0.f, 0.f};
        int k = s;
        for (; k + 8 <= e; k += 8) {
            unsigned u0 = epku[k + g];
            unsigned u1 = epku[k + 4 + g];
            int t0 = u0 >> 16, t1 = u1 >> 16;
            float d0 = __half2float(__ushort_as_half((unsigned short)(u0 & 0xFFFF)));
            float d1 = __half2float(__ushort_as_half((unsigned short)(u1 & 0xFFFF)));
            float4 w0 = *(const float4*)(ew + t0 * DD + 4 * l);
            float4 w1 = *(const float4*)(ew + t1 * DD + 4 * l);
            acc.x += w0.x * d0 + w1.x * d1;
            acc.y += w0.y * d0 + w1.y * d1;
            acc.z += w0.z * d0 + w1.z * d1;
            acc.w += w0.w * d0 + w1.w * d1;
        }
        if (k + 4 <= e) {
            unsigned u0 = epku[k + g];
            int t0 = u0 >> 16;
            float d0 = __half2float(__ushort_as_half((unsigned short)(u0 & 0xFFFF)));
            float4 w0 = *(const float4*)(ew + t0 * DD + 4 * l);
            acc.x += w0.x * d0; acc.y += w0.y * d0;
            acc.z += w0.z * d0; acc.w += w0.w * d0;
            k += 4;
        }
        if (k + g < e) {
            unsigned u0 = epku[k + g];
            int t0 = u0 >> 16;
            float d0 = __half2float(__ushort_as_half((unsigned short)(u0 & 0xFFFF)));
            float4 w0 = *(const float4*)(ew + t0 * DD + 4 * l);
            acc.x += w0.x * d0; acc.y += w0.y * d0;
            acc.z += w0.z * d0; acc.w += w0.w * d0;
        }
        acc.x += __shfl_xor(acc.x, 16, 64); acc.x += __shfl_xor(acc.x, 32, 64);
        acc.y += __shfl_xor(acc.y, 16, 64); acc.y += __shfl_xor(acc.y, 32, 64);
        acc.z += __shfl_xor(acc.z, 16, 64); acc.z += __shfl_xor(acc.z, 32, 64);
        acc.w += __shfl_xor(acc.w, 16, 64); acc.w += __shfl_xor(acc.w, 32, 64);
        int2 pc = pk[node];
        float dc = __int_as_float(pc.y);
        float4 wc = *(const float4*)(ew + pc.x * DD + 4 * l);
        float4 v;
        v.x = fmaxf((acc.x + wc.x * dc) * dc + bq.x, 0.f) * dc;
        v.y = fmaxf((acc.y + wc.y * dc) * dc + bq.y, 0.f) * dc;
        v.z = fmaxf((acc.z + wc.z * dc) * dc + bq.z, 0.f) * dc;
        v.w = fmaxf((acc.w + wc.w * dc) * dc + bq.w, 0.f) * dc;
        if (g == 0) {
            __half2 h0 = __floats2half2_rn(v.x, v.y);
            __half2 h1 = __floats2half2_rn(v.z, v.w);
            uint2 st;
            st.x = __builtin_bit_cast(unsigned, h0);
            st.y = __builtin_bit_cast(unsigned, h1);
            *(uint2*)(OUT + (long)node * DD + 4 * l) = st;
        }
    }
}

// ---- layer-2: gather v1s; t=(Σ+self)*dc; v2=relu(t@W2 + b2); OUT=fp16(v2*dc) ----
__global__ __launch_bounds__(256, 4) void k_agg2_fused(const int* __restrict__ rowptr,
                                                    const int* __restrict__ srcidx,
                                                    const float* __restrict__ dinv,
                                                    const __half* __restrict__ Hs,
                                                    const float* __restrict__ b2,
                                                    const unsigned* __restrict__ W2pk,
                                                    __half* __restrict__ OUT, int N) {
    int tid = threadIdx.x;
    int lane = tid & 63;
    int g = lane >> 4, l = lane & 15;
    unsigned Wc[32];
    #pragma unroll
    for (int p = 0; p < 32; ++p) Wc[p] = W2pk[p * DD + lane];
    float bl = b2[lane];
    int wave0 = blockIdx.x * 4 + (tid >> 6);
    int wstride = gridDim.x * 4;
    for (int node = __builtin_amdgcn_readfirstlane(wave0); node < N;
         node += wstride) {
        int s = rowptr[node], e = rowptr[node + 1];
        float4 acc = gather_sum_q(srcidx, Hs, s, e, g, l);
        float dc = dinv[node];
        uint2 sr = *(const uint2*)(Hs + (long)node * DD + 4 * l);
        float2 s0 = __half22float2(*(const __half2*)&sr.x);
        float2 s1 = __half22float2(*(const __half2*)&sr.y);
        float4 t;
        t.x = (acc.x + s0.x) * dc;
        t.y = (acc.y + s0.y) * dc;
        t.z = (acc.z + s1.x) * dc;
        t.w = (acc.w + s1.y) * dc;
        float u = epi_dot_q(t, Wc);
        float v2 = fmaxf(u + bl, 0.f);
        OUT[(long)node * DD + lane] = __float2half(v2 * dc);
    }
}

// ---- layer-3 + pooling, PUSH-style: all accesses sequential or LDS.
//      bin b holds 128 source nodes; rows staged in LDS (f32); 64x64 pool in LDS.
//      edge payload u: lrow=u>>24, graph=(u>>18)&63, dinv_c=half(u&0xFFFF).
//      pool[g][j] += dinv_c * rows[lrow][j]; plus self term per node. ----
__global__ __launch_bounds__(256) void k_push_pool(const unsigned* __restrict__ binned2,
                                                   const int* __restrict__ binstart2,
                                                   const unsigned* __restrict__ qpk,
                                                   const __half* __restrict__ Hs,
                                                   float* __restrict__ partial,
                                                   int N, int NB2) {
    __shared__ float rows[BINW2 * DD];              // 32 KB
    __shared__ float pool[NUM_GRAPHS * DD];         // 16 KB
    int b = blockIdx.x, t = threadIdx.x;
    int base = b * BINW2;
    int nn = min(N - base, BINW2);
    for (int i = t; i < NUM_GRAPHS * DD; i += 256) pool[i] = 0.0f;
    for (int i = t; i < nn * DD; i += 256)
        rows[i] = __half2float(Hs[(long)base * DD + i]);
    __syncthreads();
    int wid = t >> 6, j = t & 63;
    // self terms: node c contributes dinv_c * v2s[c] to pool[batch[c]]
    for (int node = wid; node < nn; node += 4) {
        unsigned q = qpk[base + node];
        float d = __half2float(__ushort_as_half((unsigned short)(q & 0xFFFF)));
        int g = (q >> 18) & 63;
        atomicAdd(&pool[g * DD + j], d * rows[node * DD + j]);
    }
    // edges
    int s0 = binstart2[b], s1 = binstart2[b + 1];
    int tot = s1 - s0;
    int per = (tot + 3) >> 2;
    int ks = s0 + wid * per;
    int ke = min(s1, ks + per);
    int k = ks;
    for (; k + 4 <= ke; k += 4) {
        unsigned u0 = binned2[k], u1 = binned2[k+1], u2 = binned2[k+2], u3 = binned2[k+3];
        float d0 = __half2float(__ushort_as_half((unsigned short)(u0 & 0xFFFF)));
        float d1 = __half2float(__ushort_as_half((unsigned short)(u1 & 0xFFFF)));
        float d2 = __half2float(__ushort_as_half((unsigned short)(u2 & 0xFFFF)));
        float d3 = __half2float(__ushort_as_half((unsigned short)(u3 & 0xFFFF)));
        atomicAdd(&pool[((u0 >> 18) & 63) * DD + j], d0 * rows[(u0 >> 24) * DD + j]);
        atomicAdd(&pool[((u1 >> 18) & 63) * DD + j], d1 * rows[(u1 >> 24) * DD + j]);
        atomicAdd(&pool[((u2 >> 18) & 63) * DD + j], d2 * rows[(u2 >> 24) * DD + j]);
        atomicAdd(&pool[((u3 >> 18) & 63) * DD + j], d3 * rows[(u3 >> 24) * DD + j]);
    }
    for (; k < ke; ++k) {
        unsigned u0 = binned2[k];
        float d0 = __half2float(__ushort_as_half((unsigned short)(u0 & 0xFFFF)));
        atomicAdd(&pool[((u0 >> 18) & 63) * DD + j], d0 * rows[(u0 >> 24) * DD + j]);
    }
    __syncthreads();
    for (int i = t; i < NUM_GRAPHS * DD; i += 256)
        partial[(long)b * (NUM_GRAPHS * DD) + i] = pool[i];
}

// ---- merge per-bin partial pools ----
__global__ void k_mergepool(const float* __restrict__ partial, float* __restrict__ pool,
                            int NB2) {
    int i = blockIdx.x * blockDim.x + threadIdx.x;   // 4096 threads
    float s = 0.0f;
    for (int b = 0; b < NB2; ++b) s += partial[(long)b * (NUM_GRAPHS * DD) + i];
    pool[i] = s;
}

// ---- final: per-graph W3 matmul (f32) + b3, mean, L2 normalize ----
__global__ void k_final(const float* __restrict__ pool, const int* __restrict__ batch,
                        const float* __restrict__ W3, const float* __restrict__ b3,
                        float* __restrict__ out, int N) {
    __shared__ float pr[DD];
    int g = blockIdx.x, j = threadIdx.x;
    pr[j] = pool[g * DD + j];
    __syncthreads();
    int lo = 0, hi = N;
    while (lo < hi) { int m = (lo + hi) >> 1; if (batch[m] < g) lo = m + 1; else hi = m; }
    int lo2 = lo; hi = N;
    while (lo2 < hi) { int m = (lo2 + hi) >> 1; if (batch[m] < g + 1) lo2 = m + 1; else hi = m; }
    float cnt = fmaxf((float)(lo2 - lo), 1.0f);
    float acc = 0.0f;
    #pragma unroll
    for (int d = 0; d < DD; ++d) acc += pr[d] * W3[d * DD + j];
    float v = acc / cnt + b3[j];
    float sq = v * v;
    #pragma unroll
    for (int off = 32; off > 0; off >>= 1) sq += __shfl_down(sq, off, 64);
    float nrm = __shfl(sq, 0, 64);
    out[g * DD + j] = v / sqrtf(nrm);
}

extern "C" void kernel_launch(void* const* d_in, const int* in_sizes, int n_in,
                              void* d_out, int out_size, void* d_ws, size_t ws_size,
                              hipStream_t stream) {
    const int*   node_types = (const int*)d_in[0];
    const int*   edge_index = (const int*)d_in[1];
    const int*   batch      = (const int*)d_in[2];
    const float* emb        = (const float*)d_in[3];
    const float* W1 = (const float*)d_in[4];
    const float* b1 = (const float*)d_in[5];
    const float* W2 = (const float*)d_in[6];
    const float* b2 = (const float*)d_in[7];
    const float* W3 = (const float*)d_in[8];
    const float* b3 = (const float*)d_in[9];
    const int N = in_sizes[0];
    const int E = in_sizes[1] / 2;
    const int V = in_sizes[3] / DD;
    const int* row = edge_index;
    const int* col = edge_index + E;
    const long ND = (long)N * DD;
    const int NB  = (N + BINW  - 1) / BINW;    // 391
    const int NB2 = (N + BINW2 - 1) / BINW2;   // 782
    const int CE = (E + EB - 1) / EB;

    // workspace layout
    char* p = (char*)d_ws;
    __half*   hsA      = (__half*)p;      p += ND * sizeof(__half);
    __half*   hsB      = (__half*)p;      p += ND * sizeof(__half);
    int*      srcidx   = (int*)p;         p += (size_t)E * sizeof(int);
    unsigned* epku     = (unsigned*)p;    p += (size_t)E * sizeof(unsigned);
    unsigned* binned   = (unsigned*)p;    p += (size_t)E * sizeof(unsigned);  // reused as binned2
    int*      H        = (int*)p;         p += (size_t)EB * NB * sizeof(int);
    int*      H2       = (int*)p;         p += (size_t)EB * NB2 * sizeof(int);
    int*      bintot   = (int*)p;         p += (size_t)(NB2 + 4) * sizeof(int);
    int*      binstart = (int*)p;         p += (size_t)(NB + 4) * sizeof(int);
    int*      binstart2= (int*)p;         p += (size_t)(NB2 + 4) * sizeof(int);
    float*    dinv     = (float*)p;       p += (size_t)N * sizeof(float);
    int2*     pk       = (int2*)p;        p += (size_t)N * sizeof(int2);
    unsigned* qpk      = (unsigned*)p;    p += (size_t)N * sizeof(unsigned);
    int*      rowptr   = (int*)p;         p += (size_t)(N + 4) * sizeof(int);
    float*    pool     = (float*)p;       p += (size_t)NUM_GRAPHS * DD * sizeof(float);
    float*    partial  = (float*)p;       p += (size_t)NB2 * NUM_GRAPHS * DD * sizeof(float);
    float*    embW1    = (float*)p;       p += (size_t)V * DD * sizeof(float);
    unsigned* W2pk     = (unsigned*)p;    p += 32 * DD * sizeof(unsigned);

    // ---- build 1: target-sorted CSR (for pull layers 1,2) ----
    k_hist<<<EB, 256, 0, stream>>>(col, H, E, NB, CE);
    k_scanA<<<NB, 256, 0, stream>>>(H, bintot, NB);
    k_scanB<<<1, 512, 0, stream>>>(bintot, binstart, NB);
    k_scatbin<<<EB, 256, 0, stream>>>(row, col, H, binstart, binned, E, NB, CE);
    k_bincsr<<<NB, 256, 0, stream>>>(binned, binstart, node_types, batch, srcidx, rowptr,
                                     dinv, pk, qpk, N, NB);
    k_buildepk<<<(E + 255) / 256, 256, 0, stream>>>(srcidx, pk, epku, E);

    // ---- build 2: source-binned push payloads (for layer 3) ----
    k_hist2<<<EB, 256, 0, stream>>>(row, H2, E, NB2, CE);
    k_scanA<<<NB2, 256, 0, stream>>>(H2, bintot, NB2);
    k_scanB2<<<1, 1024, 0, stream>>>(bintot, binstart2, NB2);
    k_scatbin2<<<EB, 256, 0, stream>>>(row, col, H2, binstart2, qpk, binned, E, NB2, CE);

    // ---- weight prep ----
    k_embW1<<<V, DD, 0, stream>>>(emb, W1, embW1, V);
    k_packW<<<8, 256, 0, stream>>>(W2, W2pk);

    // ---- layer 1 -> v1s fp16 ----
    k_agg1_fused<<<AGG_BLOCKS, 256, 0, stream>>>(rowptr, epku, pk, embW1, b1,
                                                 hsA, N, V);
    // ---- layer 2 -> v2s fp16 ----
    k_agg2_fused<<<AGG_BLOCKS, 256, 0, stream>>>(rowptr, srcidx, dinv, hsA, b2, W2pk,
                                                 hsB, N);
    // ---- layer 3 + pooling, push-style ----
    k_push_pool<<<NB2, 256, 0, stream>>>(binned, binstart2, qpk, hsB, partial, N, NB2);
    k_mergepool<<<16, 256, 0, stream>>>(partial, pool, NB2);

    // ---- per-graph W3 + b3 + mean + normalize ----
    k_final<<<NUM_GRAPHS, DD, 0, stream>>>(pool, batch, W3, b3, (float*)d_out, N);
}

// Round 16
// 406.205 us; speedup vs baseline: 2.9386x; 2.9386x over previous
//
#include <hip/hip_runtime.h>
#include <hip/hip_fp16.h>

#define DD 64
#define NUM_GRAPHS 64
#define AGG_BLOCKS 2048
#define EB 512          // edge-blocks for hist/scatter passes
#define BINW 256        // nodes per bin (target-sorted build)
#define BINW2 128       // nodes per bin (source-sorted push build)
#define MAXNB 512
#define MAXNB2 1024
#define EBIN_CAP 6144
#define EBIN2_CAP 3072  // push bin: mean 2048+128 self, sd ~45

typedef _Float16 h2_t __attribute__((ext_vector_type(2)));

__device__ __forceinline__ float fdot2u(unsigned a, unsigned b, float c) {
    return __builtin_amdgcn_fdot2(__builtin_bit_cast(h2_t, a),
                                  __builtin_bit_cast(h2_t, b), c, false);
}

// ---- pass A: per-edge-block histogram over target bins ----
__global__ __launch_bounds__(256) void k_hist(const int* __restrict__ col,
                                              int* __restrict__ H, int E, int NB, int CE) {
    __shared__ int h[MAXNB];
    int eb = blockIdx.x, t = threadIdx.x;
    for (int i = t; i < NB; i += 256) h[i] = 0;
    __syncthreads();
    int e0 = eb * CE, e1 = min(E, e0 + CE);
    for (int e = e0 + t; e < e1; e += 256) atomicAdd(&h[col[e] >> 8], 1);
    __syncthreads();
    for (int i = t; i < NB; i += 256) H[eb * NB + i] = h[i];
}

// ---- histogram over SOURCE bins (BINW2=128) ----
__global__ __launch_bounds__(256) void k_hist2(const int* __restrict__ row,
                                               int* __restrict__ H, int E, int NB, int CE) {
    __shared__ int h[MAXNB2];
    int eb = blockIdx.x, t = threadIdx.x;
    for (int i = t; i < NB; i += 256) h[i] = 0;
    __syncthreads();
    int e0 = eb * CE, e1 = min(E, e0 + CE);
    for (int e = e0 + t; e < e1; e += 256) atomicAdd(&h[row[e] >> 7], 1);
    __syncthreads();
    for (int i = t; i < NB; i += 256) H[eb * NB + i] = h[i];
}

// ---- per-bin exclusive scan over the EB edge-blocks ----
__global__ __launch_bounds__(256) void k_scanA(int* __restrict__ H,
                                               int* __restrict__ bintot, int NB) {
    __shared__ int s[256];
    int b = blockIdx.x, t = threadIdx.x;
    int i0 = (2 * t) * NB + b, i1 = (2 * t + 1) * NB + b;
    int v0 = H[i0], v1 = H[i1];
    int tot = v0 + v1;
    s[t] = tot;
    __syncthreads();
    for (int off = 1; off < 256; off <<= 1) {
        int tv = (t >= off) ? s[t - off] : 0;
        __syncthreads();
        s[t] += tv;
        __syncthreads();
    }
    int excl = s[t] - tot;
    H[i0] = excl;
    H[i1] = excl + v0;
    if (t == 255) bintot[b] = s[255];
}

// ---- scan bin totals (≤512 bins) ----
__global__ void k_scanB(const int* __restrict__ bintot, int* __restrict__ binstart, int NB) {
    __shared__ int s[512];
    int t = threadIdx.x;
    int v = (t < NB) ? bintot[t] : 0;
    s[t] = v;
    __syncthreads();
    for (int off = 1; off < 512; off <<= 1) {
        int tv = (t >= off) ? s[t - off] : 0;
        __syncthreads();
        s[t] += tv;
        __syncthreads();
    }
    if (t < NB) binstart[t] = s[t] - v;
    if (t == 511) binstart[NB] = s[511];
}

// ---- scan bin totals (≤1024 bins) ----
__global__ void k_scanB2(const int* __restrict__ bintot, int* __restrict__ binstart, int NB) {
    __shared__ int s[1024];
    int t = threadIdx.x;
    int v = (t < NB) ? bintot[t] : 0;
    s[t] = v;
    __syncthreads();
    for (int off = 1; off < 1024; off <<= 1) {
        int tv = (t >= off) ? s[t - off] : 0;
        __syncthreads();
        s[t] += tv;
        __syncthreads();
    }
    if (t < NB) binstart[t] = s[t] - v;
    if (t == 1023) binstart[NB] = s[1023];
}

// ---- scatter packed edges into target-bin regions ----
__global__ __launch_bounds__(256) void k_scatbin(const int* __restrict__ row,
                                                 const int* __restrict__ col,
                                                 const int* __restrict__ H,
                                                 const int* __restrict__ binstart,
                                                 unsigned* __restrict__ binned,
                                                 int E, int NB, int CE) {
    __shared__ int off[MAXNB];
    int eb = blockIdx.x, t = threadIdx.x;
    for (int i = t; i < NB; i += 256) off[i] = binstart[i] + H[eb * NB + i];
    __syncthreads();
    int e0 = eb * CE, e1 = min(E, e0 + CE);
    for (int e = e0 + t; e < e1; e += 256) {
        int c = col[e], r = row[e];
        int slot = atomicAdd(&off[c >> 8], 1);
        binned[slot] = ((unsigned)(c & 255) << 24) | (unsigned)r;
    }
}

// ---- scatter push payloads into SOURCE-bin regions:
//      payload = (localrow<<24) | qpk[col]   (qpk = batch<<18 | half(dinv)) ----
__global__ __launch_bounds__(256) void k_scatbin2(const int* __restrict__ row,
                                                  const int* __restrict__ col,
                                                  const int* __restrict__ H,
                                                  const int* __restrict__ binstart,
                                                  const unsigned* __restrict__ qpk,
                                                  unsigned* __restrict__ binned,
                                                  int E, int NB, int CE) {
    __shared__ int off[MAXNB2];
    int eb = blockIdx.x, t = threadIdx.x;
    for (int i = t; i < NB; i += 256) off[i] = binstart[i] + H[eb * NB + i];
    __syncthreads();
    int e0 = eb * CE, e1 = min(E, e0 + CE);
    for (int e = e0 + t; e < e1; e += 256) {
        int r = row[e], c = col[e];
        int slot = atomicAdd(&off[r >> 7], 1);
        binned[slot] = ((unsigned)(r & 127) << 24) | qpk[c];
    }
}

// ---- per-bin CSR finalize in LDS; also emits qpk ----
__global__ __launch_bounds__(256) void k_bincsr(const unsigned* __restrict__ binned,
                                                const int* __restrict__ binstart,
                                                const int* __restrict__ nt,
                                                const int* __restrict__ batch,
                                                int* __restrict__ srcidx,
                                                int* __restrict__ rowptr,
                                                float* __restrict__ dinv,
                                                int2* __restrict__ pk,
                                                unsigned* __restrict__ qpk, int N, int NB) {
    __shared__ unsigned arr[EBIN_CAP];
    __shared__ int sorted_[EBIN_CAP];
    __shared__ int cnt[BINW];
    __shared__ int base[BINW];
    __shared__ int cursor[BINW];
    int b = blockIdx.x, t = threadIdx.x;
    int s0 = binstart[b], s1 = binstart[b + 1];
    int binsz = s1 - s0;
    if (binsz > EBIN_CAP) binsz = EBIN_CAP;
    cnt[t] = 0;
    for (int i = t; i < binsz; i += 256) arr[i] = binned[s0 + i];
    __syncthreads();
    for (int i = t; i < binsz; i += 256) atomicAdd(&cnt[arr[i] >> 24], 1);
    __syncthreads();
    int v = cnt[t];
    base[t] = v;
    __syncthreads();
    for (int off = 1; off < 256; off <<= 1) {
        int tv = (t >= off) ? base[t - off] : 0;
        __syncthreads();
        base[t] += tv;
        __syncthreads();
    }
    int excl = base[t] - v;
    __syncthreads();
    base[t] = excl;
    cursor[t] = excl;
    __syncthreads();
    for (int i = t; i < binsz; i += 256) {
        unsigned val = arr[i];
        int pos = atomicAdd(&cursor[val >> 24], 1);
        sorted_[pos] = (int)(val & 0xFFFFFF);
    }
    __syncthreads();
    for (int i = t; i < binsz; i += 256) srcidx[s0 + i] = sorted_[i];
    int node = b * BINW + t;
    if (node < N) {
        rowptr[node] = s0 + base[t];
        float di = rsqrtf((float)cnt[t] + 1.0f);   // +1 = self loop
        dinv[node] = di;
        pk[node] = make_int2(nt[node], __float_as_int(di));
        qpk[node] = ((unsigned)batch[node] << 18) |
                    (unsigned)__half_as_ushort(__float2half(di));
    }
    if (b == NB - 1 && t == 0) rowptr[N] = s1;
}

// ---- per-edge packed operand in CSR order ----
__global__ void k_buildepk(const int* __restrict__ srcidx, const int2* __restrict__ pk,
                           unsigned* __restrict__ epku, int E) {
    int i = blockIdx.x * blockDim.x + threadIdx.x;
    if (i >= E) return;
    int2 p = pk[srcidx[i]];
    epku[i] = ((unsigned)p.x << 16) |
              (unsigned)__half_as_ushort(__float2half(__int_as_float(p.y)));
}

// ---- embW1 = emb_table @ W1 ----
__global__ void k_embW1(const float* __restrict__ emb, const float* __restrict__ W1,
                        float* __restrict__ embW1, int V) {
    __shared__ float er[DD];
    int v = blockIdx.x, j = threadIdx.x;
    er[j] = emb[v * DD + j];
    __syncthreads();
    float acc = 0.0f;
    #pragma unroll
    for (int d = 0; d < DD; ++d) acc += er[d] * W1[d * DD + j];
    embW1[v * DD + j] = acc;
}

// ---- pack W into half2 pairs ----
__global__ void k_packW(const float* __restrict__ W, unsigned* __restrict__ Wpk) {
    int t = blockIdx.x * blockDim.x + threadIdx.x;
    if (t >= 32 * DD) return;
    int p = t >> 6, j = t & 63;
    __half2 h = __floats2half2_rn(W[(2 * p) * DD + j], W[(2 * p + 1) * DD + j]);
    Wpk[t] = __builtin_bit_cast(unsigned, h);
}

// epilogue dot, v distributed 4 features/lane
__device__ __forceinline__ float epi_dot_q(float4 v, const unsigned* Wc) {
    __half2 h0 = __floats2half2_rn(v.x, v.y);
    __half2 h1 = __floats2half2_rn(v.z, v.w);
    int vp0 = __builtin_bit_cast(int, h0);
    int vp1 = __builtin_bit_cast(int, h1);
    float o0 = 0.f, o1 = 0.f, o2 = 0.f, o3 = 0.f;
    #pragma unroll
    for (int p = 0; p < 32; p += 4) {
        o0 = fdot2u((unsigned)__builtin_amdgcn_readlane(vp0, (p + 0) >> 1), Wc[p + 0], o0);
        o1 = fdot2u((unsigned)__builtin_amdgcn_readlane(vp1, (p + 1) >> 1), Wc[p + 1], o1);
        o2 = fdot2u((unsigned)__builtin_amdgcn_readlane(vp0, (p + 2) >> 1), Wc[p + 2], o2);
        o3 = fdot2u((unsigned)__builtin_amdgcn_readlane(vp1, (p + 3) >> 1), Wc[p + 3], o3);
    }
    return (o0 + o1) + (o2 + o3);
}

__device__ __forceinline__ void acc_h4(float4& a, uint2 r) {
    float2 f0 = __half22float2(*(const __half2*)&r.x);
    float2 f1 = __half22float2(*(const __half2*)&r.y);
    a.x += f0.x; a.y += f0.y; a.z += f1.x; a.w += f1.y;
}

// quarter-wave gather, 2-stage software pipeline
__device__ __forceinline__ float4 gather_sum_q(const int* __restrict__ srcidx,
                                               const __half* __restrict__ Hs,
                                               int s, int e, int g, int l) {
    float4 A = {0,0,0,0}, B = {0,0,0,0}, C = {0,0,0,0}, D = {0,0,0,0};
    int k = s;
    int kend = s + ((e - s) & ~15);
    if (k < kend) {
        uint2 r0 = *(const uint2*)(Hs + (long)srcidx[k + g] * DD + 4 * l);
        uint2 r1 = *(const uint2*)(Hs + (long)srcidx[k + 4 + g] * DD + 4 * l);
        uint2 r2 = *(const uint2*)(Hs + (long)srcidx[k + 8 + g] * DD + 4 * l);
        uint2 r3 = *(const uint2*)(Hs + (long)srcidx[k + 12 + g] * DD + 4 * l);
        k += 16;
        for (; k < kend; k += 16) {
            uint2 n0 = *(const uint2*)(Hs + (long)srcidx[k + g] * DD + 4 * l);
            uint2 n1 = *(const uint2*)(Hs + (long)srcidx[k + 4 + g] * DD + 4 * l);
            uint2 n2 = *(const uint2*)(Hs + (long)srcidx[k + 8 + g] * DD + 4 * l);
            uint2 n3 = *(const uint2*)(Hs + (long)srcidx[k + 12 + g] * DD + 4 * l);
            acc_h4(A, r0); acc_h4(B, r1); acc_h4(C, r2); acc_h4(D, r3);
            r0 = n0; r1 = n1; r2 = n2; r3 = n3;
        }
        acc_h4(A, r0); acc_h4(B, r1); acc_h4(C, r2); acc_h4(D, r3);
    }
    for (; k < e; k += 4) {
        if (k + g < e) {
            uint2 rr = *(const uint2*)(Hs + (long)srcidx[k + g] * DD + 4 * l);
            acc_h4(A, rr);
        }
    }
    A.x += B.x + C.x + D.x; A.y += B.y + C.y + D.y;
    A.z += B.z + C.z + D.z; A.w += B.w + C.w + D.w;
    A.x += __shfl_xor(A.x, 16, 64); A.x += __shfl_xor(A.x, 32, 64);
    A.y += __shfl_xor(A.y, 16, 64); A.y += __shfl_xor(A.y, 32, 64);
    A.z += __shfl_xor(A.z, 16, 64); A.z += __shfl_xor(A.z, 32, 64);
    A.w += __shfl_xor(A.w, 16, 64); A.w += __shfl_xor(A.w, 32, 64);
    return A;
}

// ---- layer-1, quarter-wave (LDS ew table; no matmul) ----
__global__ __launch_bounds__(256, 4) void k_agg1_fused(const int* __restrict__ rowptr,
                                                    const unsigned* __restrict__ epku,
                                                    const int2* __restrict__ pk,
                                                    const float* __restrict__ embW1,
                                                    const float* __restrict__ b1,
                                                    __half* __restrict__ OUT, int N, int V) {
    __shared__ float ew[30 * DD];
    int tid = threadIdx.x;
    for (int k = tid; k < V * DD; k += 256) ew[k] = embW1[k];
    __syncthreads();
    int lane = tid & 63;
    int g = lane >> 4, l = lane & 15;
    float4 bq = *(const float4*)(b1 + 4 * l);
    int wave0 = blockIdx.x * 4 + (tid >> 6);
    int wstride = gridDim.x * 4;
    for (int node = __builtin_amdgcn_readfirstlane(wave0); node < N;
         node += wstride) {
        int s = rowptr[node], e = rowptr[node + 1];
        float4 acc = {0.f, 0.f, 0.f, 0.f};
        int k = s;
        for (; k + 8 <= e; k += 8) {
            unsigned u0 = epku[k + g];
            unsigned u1 = epku[k + 4 + g];
            int t0 = u0 >> 16, t1 = u1 >> 16;
            float d0 = __half2float(__ushort_as_half((unsigned short)(u0 & 0xFFFF)));
            float d1 = __half2float(__ushort_as_half((unsigned short)(u1 & 0xFFFF)));
            float4 w0 = *(const float4*)(ew + t0 * DD + 4 * l);
            float4 w1 = *(const float4*)(ew + t1 * DD + 4 * l);
            acc.x += w0.x * d0 + w1.x * d1;
            acc.y += w0.y * d0 + w1.y * d1;
            acc.z += w0.z * d0 + w1.z * d1;
            acc.w += w0.w * d0 + w1.w * d1;
        }
        if (k + 4 <= e) {
            unsigned u0 = epku[k + g];
            int t0 = u0 >> 16;
            float d0 = __half2float(__ushort_as_half((unsigned short)(u0 & 0xFFFF)));
            float4 w0 = *(const float4*)(ew + t0 * DD + 4 * l);
            acc.x += w0.x * d0; acc.y += w0.y * d0;
            acc.z += w0.z * d0; acc.w += w0.w * d0;
            k += 4;
        }
        if (k + g < e) {
            unsigned u0 = epku[k + g];
            int t0 = u0 >> 16;
            float d0 = __half2float(__ushort_as_half((unsigned short)(u0 & 0xFFFF)));
            float4 w0 = *(const float4*)(ew + t0 * DD + 4 * l);
            acc.x += w0.x * d0; acc.y += w0.y * d0;
            acc.z += w0.z * d0; acc.w += w0.w * d0;
        }
        acc.x += __shfl_xor(acc.x, 16, 64); acc.x += __shfl_xor(acc.x, 32, 64);
        acc.y += __shfl_xor(acc.y, 16, 64); acc.y += __shfl_xor(acc.y, 32, 64);
        acc.z += __shfl_xor(acc.z, 16, 64); acc.z += __shfl_xor(acc.z, 32, 64);
        acc.w += __shfl_xor(acc.w, 16, 64); acc.w += __shfl_xor(acc.w, 32, 64);
        int2 pc = pk[node];
        float dc = __int_as_float(pc.y);
        float4 wc = *(const float4*)(ew + pc.x * DD + 4 * l);
        float4 v;
        v.x = fmaxf((acc.x + wc.x * dc) * dc + bq.x, 0.f) * dc;
        v.y = fmaxf((acc.y + wc.y * dc) * dc + bq.y, 0.f) * dc;
        v.z = fmaxf((acc.z + wc.z * dc) * dc + bq.z, 0.f) * dc;
        v.w = fmaxf((acc.w + wc.w * dc) * dc + bq.w, 0.f) * dc;
        if (g == 0) {
            __half2 h0 = __floats2half2_rn(v.x, v.y);
            __half2 h1 = __floats2half2_rn(v.z, v.w);
            uint2 st;
            st.x = __builtin_bit_cast(unsigned, h0);
            st.y = __builtin_bit_cast(unsigned, h1);
            *(uint2*)(OUT + (long)node * DD + 4 * l) = st;
        }
    }
}

// ---- layer-2: gather v1s; t=(Σ+self)*dc; v2=relu(t@W2 + b2); OUT=fp16(v2*dc) ----
__global__ __launch_bounds__(256, 4) void k_agg2_fused(const int* __restrict__ rowptr,
                                                    const int* __restrict__ srcidx,
                                                    const float* __restrict__ dinv,
                                                    const __half* __restrict__ Hs,
                                                    const float* __restrict__ b2,
                                                    const unsigned* __restrict__ W2pk,
                                                    __half* __restrict__ OUT, int N) {
    int tid = threadIdx.x;
    int lane = tid & 63;
    int g = lane >> 4, l = lane & 15;
    unsigned Wc[32];
    #pragma unroll
    for (int p = 0; p < 32; ++p) Wc[p] = W2pk[p * DD + lane];
    float bl = b2[lane];
    int wave0 = blockIdx.x * 4 + (tid >> 6);
    int wstride = gridDim.x * 4;
    for (int node = __builtin_amdgcn_readfirstlane(wave0); node < N;
         node += wstride) {
        int s = rowptr[node], e = rowptr[node + 1];
        float4 acc = gather_sum_q(srcidx, Hs, s, e, g, l);
        float dc = dinv[node];
        uint2 sr = *(const uint2*)(Hs + (long)node * DD + 4 * l);
        float2 s0 = __half22float2(*(const __half2*)&sr.x);
        float2 s1 = __half22float2(*(const __half2*)&sr.y);
        float4 t;
        t.x = (acc.x + s0.x) * dc;
        t.y = (acc.y + s0.y) * dc;
        t.z = (acc.z + s1.x) * dc;
        t.w = (acc.w + s1.y) * dc;
        float u = epi_dot_q(t, Wc);
        float v2 = fmaxf(u + bl, 0.f);
        OUT[(long)node * DD + lane] = __float2half(v2 * dc);
    }
}

// ---- layer-3 + pooling, PUSH-style v2:
//      payloads staged in LDS, counting-sorted by graph g, traversed with
//      REGISTER accumulation (flush on g-change only). All traffic LDS/sequential. ----
__global__ __launch_bounds__(256) void k_push_pool(const unsigned* __restrict__ binned2,
                                                   const int* __restrict__ binstart2,
                                                   const unsigned* __restrict__ qpk,
                                                   const __half* __restrict__ Hs,
                                                   float* __restrict__ partial,
                                                   int N, int NB2) {
    __shared__ float rows[BINW2 * DD];       // 32 KB
    __shared__ float pool[NUM_GRAPHS * DD];  // 16 KB
    __shared__ unsigned arr[EBIN2_CAP];      // 12 KB
    __shared__ unsigned srt[EBIN2_CAP];      // 12 KB
    __shared__ int gcur[NUM_GRAPHS];
    __shared__ int gcnt[NUM_GRAPHS];
    int b = blockIdx.x, t = threadIdx.x;
    int base = b * BINW2;
    if (base >= N) return;
    int nn = min(N - base, BINW2);
    for (int i = t; i < NUM_GRAPHS * DD; i += 256) pool[i] = 0.0f;
    if (t < NUM_GRAPHS) gcnt[t] = 0;
    // stage rows (coalesced uint2 = 4 halves)
    for (int i = t; i < nn * (DD / 4); i += 256) {
        uint2 h4 = ((const uint2*)(Hs + (long)base * DD))[i];
        float2 f0 = __half22float2(*(const __half2*)&h4.x);
        float2 f1 = __half22float2(*(const __half2*)&h4.y);
        rows[i * 4 + 0] = f0.x; rows[i * 4 + 1] = f0.y;
        rows[i * 4 + 2] = f1.x; rows[i * 4 + 3] = f1.y;
    }
    // stage payloads (coalesced) + self terms appended
    int s0 = binstart2[b], s1 = binstart2[b + 1];
    int tot = s1 - s0;
    if (tot > EBIN2_CAP - nn) tot = EBIN2_CAP - nn;   // statistically impossible
    int M = tot + nn;
    for (int i = t; i < tot; i += 256) arr[i] = binned2[s0 + i];
    for (int i = t; i < nn; i += 256) arr[tot + i] = ((unsigned)i << 24) | qpk[base + i];
    __syncthreads();
    // histogram by g (native int LDS atomics)
    for (int i = t; i < M; i += 256) atomicAdd(&gcnt[(arr[i] >> 18) & 63], 1);
    __syncthreads();
    // exclusive scan over 64 graph counters (single wave, shfl)
    if (t < 64) {
        int v = gcnt[t];
        int acc = v;
        for (int off = 1; off < 64; off <<= 1) {
            int nv = __shfl_up(acc, off, 64);
            if (t >= off) acc += nv;
        }
        gcur[t] = acc - v;
    }
    __syncthreads();
    // scatter -> sorted by g
    for (int i = t; i < M; i += 256) {
        unsigned u = arr[i];
        int pos = atomicAdd(&gcur[(u >> 18) & 63], 1);
        srt[pos] = u;
    }
    __syncthreads();
    // sorted traversal: wave w covers [w*per, ...), register accumulation
    int wid = t >> 6, j = t & 63;
    int per = (M + 3) >> 2;
    int ks = wid * per;
    int ke = min(M, ks + per);
    if (ks < ke) {
        unsigned u0 = srt[ks];
        int curg = (u0 >> 18) & 63;
        float acc = __half2float(__ushort_as_half((unsigned short)(u0 & 0xFFFF)))
                    * rows[(u0 >> 24) * DD + j];
        int k = ks + 1;
        for (; k + 4 <= ke; k += 4) {
            unsigned a0 = srt[k], a1 = srt[k+1], a2 = srt[k+2], a3 = srt[k+3];
            float r0 = rows[(a0 >> 24) * DD + j];
            float r1 = rows[(a1 >> 24) * DD + j];
            float r2 = rows[(a2 >> 24) * DD + j];
            float r3 = rows[(a3 >> 24) * DD + j];
            int g0 = (a0 >> 18) & 63, g1 = (a1 >> 18) & 63;
            int g2 = (a2 >> 18) & 63, g3 = (a3 >> 18) & 63;
            float d0 = __half2float(__ushort_as_half((unsigned short)(a0 & 0xFFFF)));
            float d1 = __half2float(__ushort_as_half((unsigned short)(a1 & 0xFFFF)));
            float d2 = __half2float(__ushort_as_half((unsigned short)(a2 & 0xFFFF)));
            float d3 = __half2float(__ushort_as_half((unsigned short)(a3 & 0xFFFF)));
            if (g0 != curg) { atomicAdd(&pool[curg * DD + j], acc); curg = g0; acc = d0 * r0; }
            else acc += d0 * r0;
            if (g1 != curg) { atomicAdd(&pool[curg * DD + j], acc); curg = g1; acc = d1 * r1; }
            else acc += d1 * r1;
            if (g2 != curg) { atomicAdd(&pool[curg * DD + j], acc); curg = g2; acc = d2 * r2; }
            else acc += d2 * r2;
            if (g3 != curg) { atomicAdd(&pool[curg * DD + j], acc); curg = g3; acc = d3 * r3; }
            else acc += d3 * r3;
        }
        for (; k < ke; ++k) {
            unsigned u = srt[k];
            int g = (u >> 18) & 63;
            float d = __half2float(__ushort_as_half((unsigned short)(u & 0xFFFF)));
            float val = d * rows[(u >> 24) * DD + j];
            if (g != curg) { atomicAdd(&pool[curg * DD + j], acc); curg = g; acc = val; }
            else acc += val;
        }
        atomicAdd(&pool[curg * DD + j], acc);
    }
    __syncthreads();
    for (int i = t; i < NUM_GRAPHS * DD; i += 256)
        partial[(long)b * (NUM_GRAPHS * DD) + i] = pool[i];
}

// ---- merge per-bin partial pools: 128 blocks = 16 i-blocks x 8 b-chunks ----
__global__ void k_mergepool(const float* __restrict__ partial, float* __restrict__ pool,
                            int NB2) {
    int ib = blockIdx.x & 15, bc = blockIdx.x >> 4;
    int i = ib * 256 + threadIdx.x;
    int chunk = (NB2 + 7) / 8;
    int b0 = bc * chunk, b1 = min(NB2, b0 + chunk);
    float s = 0.0f;
    for (int b = b0; b < b1; ++b) s += partial[(long)b * (NUM_GRAPHS * DD) + i];
    atomicAdd(&pool[i], s);
}

// ---- final: per-graph W3 matmul (f32) + b3, mean, L2 normalize ----
__global__ void k_final(const float* __restrict__ pool, const int* __restrict__ batch,
                        const float* __restrict__ W3, const float* __restrict__ b3,
                        float* __restrict__ out, int N) {
    __shared__ float pr[DD];
    int g = blockIdx.x, j = threadIdx.x;
    pr[j] = pool[g * DD + j];
    __syncthreads();
    int lo = 0, hi = N;
    while (lo < hi) { int m = (lo + hi) >> 1; if (batch[m] < g) lo = m + 1; else hi = m; }
    int lo2 = lo; hi = N;
    while (lo2 < hi) { int m = (lo2 + hi) >> 1; if (batch[m] < g + 1) lo2 = m + 1; else hi = m; }
    float cnt = fmaxf((float)(lo2 - lo), 1.0f);
    float acc = 0.0f;
    #pragma unroll
    for (int d = 0; d < DD; ++d) acc += pr[d] * W3[d * DD + j];
    float v = acc / cnt + b3[j];
    float sq = v * v;
    #pragma unroll
    for (int off = 32; off > 0; off >>= 1) sq += __shfl_down(sq, off, 64);
    float nrm = __shfl(sq, 0, 64);
    out[g * DD + j] = v / sqrtf(nrm);
}

extern "C" void kernel_launch(void* const* d_in, const int* in_sizes, int n_in,
                              void* d_out, int out_size, void* d_ws, size_t ws_size,
                              hipStream_t stream) {
    const int*   node_types = (const int*)d_in[0];
    const int*   edge_index = (const int*)d_in[1];
    const int*   batch      = (const int*)d_in[2];
    const float* emb        = (const float*)d_in[3];
    const float* W1 = (const float*)d_in[4];
    const float* b1 = (const float*)d_in[5];
    const float* W2 = (const float*)d_in[6];
    const float* b2 = (const float*)d_in[7];
    const float* W3 = (const float*)d_in[8];
    const float* b3 = (const float*)d_in[9];
    const int N = in_sizes[0];
    const int E = in_sizes[1] / 2;
    const int V = in_sizes[3] / DD;
    const int* row = edge_index;
    const int* col = edge_index + E;
    const long ND = (long)N * DD;
    const int NB  = (N + BINW  - 1) / BINW;    // 391
    const int NB2 = (N + BINW2 - 1) / BINW2;   // 782
    const int CE = (E + EB - 1) / EB;

    // workspace layout
    char* p = (char*)d_ws;
    __half*   hsA      = (__half*)p;      p += ND * sizeof(__half);
    __half*   hsB      = (__half*)p;      p += ND * sizeof(__half);
    int*      srcidx   = (int*)p;         p += (size_t)E * sizeof(int);
    unsigned* epku     = (unsigned*)p;    p += (size_t)E * sizeof(unsigned);
    unsigned* binned   = (unsigned*)p;    p += (size_t)E * sizeof(unsigned);  // reused as binned2
    int*      H        = (int*)p;         p += (size_t)EB * NB * sizeof(int);
    int*      H2       = (int*)p;         p += (size_t)EB * NB2 * sizeof(int);
    int*      bintot   = (int*)p;         p += (size_t)(NB2 + 4) * sizeof(int);
    int*      binstart = (int*)p;         p += (size_t)(NB + 4) * sizeof(int);
    int*      binstart2= (int*)p;         p += (size_t)(NB2 + 4) * sizeof(int);
    float*    dinv     = (float*)p;       p += (size_t)N * sizeof(float);
    int2*     pk       = (int2*)p;        p += (size_t)N * sizeof(int2);
    unsigned* qpk      = (unsigned*)p;    p += (size_t)N * sizeof(unsigned);
    int*      rowptr   = (int*)p;         p += (size_t)(N + 4) * sizeof(int);
    float*    pool     = (float*)p;       p += (size_t)NUM_GRAPHS * DD * sizeof(float);
    float*    partial  = (float*)p;       p += (size_t)NB2 * NUM_GRAPHS * DD * sizeof(float);
    float*    embW1    = (float*)p;       p += (size_t)V * DD * sizeof(float);
    unsigned* W2pk     = (unsigned*)p;    p += 32 * DD * sizeof(unsigned);

    // ---- build 1: target-sorted CSR (for pull layers 1,2) ----
    k_hist<<<EB, 256, 0, stream>>>(col, H, E, NB, CE);
    k_scanA<<<NB, 256, 0, stream>>>(H, bintot, NB);
    k_scanB<<<1, 512, 0, stream>>>(bintot, binstart, NB);
    k_scatbin<<<EB, 256, 0, stream>>>(row, col, H, binstart, binned, E, NB, CE);
    k_bincsr<<<NB, 256, 0, stream>>>(binned, binstart, node_types, batch, srcidx, rowptr,
                                     dinv, pk, qpk, N, NB);
    k_buildepk<<<(E + 255) / 256, 256, 0, stream>>>(srcidx, pk, epku, E);

    // ---- build 2: source-binned push payloads (for layer 3) ----
    k_hist2<<<EB, 256, 0, stream>>>(row, H2, E, NB2, CE);
    k_scanA<<<NB2, 256, 0, stream>>>(H2, bintot, NB2);
    k_scanB2<<<1, 1024, 0, stream>>>(bintot, binstart2, NB2);
    k_scatbin2<<<EB, 256, 0, stream>>>(row, col, H2, binstart2, qpk, binned, E, NB2, CE);

    // ---- weight prep ----
    k_embW1<<<V, DD, 0, stream>>>(emb, W1, embW1, V);
    k_packW<<<8, 256, 0, stream>>>(W2, W2pk);

    // ---- layer 1 -> v1s fp16 ----
    k_agg1_fused<<<AGG_BLOCKS, 256, 0, stream>>>(rowptr, epku, pk, embW1, b1,
                                                 hsA, N, V);
    // ---- layer 2 -> v2s fp16 ----
    k_agg2_fused<<<AGG_BLOCKS, 256, 0, stream>>>(rowptr, srcidx, dinv, hsA, b2, W2pk,
                                                 hsB, N);
    // ---- layer 3 + pooling, push-style v2 ----
    k_push_pool<<<NB2, 256, 0, stream>>>(binned, binstart2, qpk, hsB, partial, N, NB2);
    hipMemsetAsync(pool, 0, (size_t)(NUM_GRAPHS * DD) * sizeof(float), stream);
    k_mergepool<<<128, 256, 0, stream>>>(partial, pool, NB2);

    // ---- per-graph W3 + b3 + mean + normalize ----
    k_final<<<NUM_GRAPHS, DD, 0, stream>>>(pool, batch, W3, b3, (float*)d_out, N);
}

// Round 17
// 296.800 us; speedup vs baseline: 4.0218x; 1.3686x over previous
//
#include <hip/hip_runtime.h>
#include <hip/hip_fp16.h>

#define DD 64
#define NUM_GRAPHS 64
#define AGG_BLOCKS 2048
#define EB 512          // edge-blocks for hist/scatter passes
#define BINW 256        // nodes per bin
#define MAXNB 512       // LDS capacity for bin counters
#define EBIN_CAP 6144   // max edges per bin staged in LDS (mean 4096, sd 64)

typedef _Float16 h2_t __attribute__((ext_vector_type(2)));

__device__ __forceinline__ float fdot2u(unsigned a, unsigned b, float c) {
    return __builtin_amdgcn_fdot2(__builtin_bit_cast(h2_t, a),
                                  __builtin_bit_cast(h2_t, b), c, false);
}

// ---- pass A: per-edge-block histogram over bins (LDS atomics only) ----
__global__ __launch_bounds__(256) void k_hist(const int* __restrict__ col,
                                              int* __restrict__ H, int E, int NB, int CE) {
    __shared__ int h[MAXNB];
    int eb = blockIdx.x, t = threadIdx.x;
    for (int i = t; i < NB; i += 256) h[i] = 0;
    __syncthreads();
    int e0 = eb * CE, e1 = min(E, e0 + CE);
    for (int e = e0 + t; e < e1; e += 256) atomicAdd(&h[col[e] >> 8], 1);
    __syncthreads();
    for (int i = t; i < NB; i += 256) H[eb * NB + i] = h[i];
}

// ---- pass B1: per-bin exclusive scan over edge-blocks ----
__global__ __launch_bounds__(256) void k_scanA(int* __restrict__ H,
                                               int* __restrict__ bintot, int NB) {
    __shared__ int s[256];
    int b = blockIdx.x, t = threadIdx.x;
    int i0 = (2 * t) * NB + b, i1 = (2 * t + 1) * NB + b;
    int v0 = H[i0], v1 = H[i1];
    int tot = v0 + v1;
    s[t] = tot;
    __syncthreads();
    for (int off = 1; off < 256; off <<= 1) {
        int tv = (t >= off) ? s[t - off] : 0;
        __syncthreads();
        s[t] += tv;
        __syncthreads();
    }
    int excl = s[t] - tot;
    H[i0] = excl;
    H[i1] = excl + v0;
    if (t == 255) bintot[b] = s[255];
}

// ---- pass B2: scan bin totals ----
__global__ void k_scanB(const int* __restrict__ bintot, int* __restrict__ binstart, int NB) {
    __shared__ int s[512];
    int t = threadIdx.x;
    int v = (t < NB) ? bintot[t] : 0;
    s[t] = v;
    __syncthreads();
    for (int off = 1; off < 512; off <<= 1) {
        int tv = (t >= off) ? s[t - off] : 0;
        __syncthreads();
        s[t] += tv;
        __syncthreads();
    }
    if (t < NB) binstart[t] = s[t] - v;
    if (t == 511) binstart[NB] = s[511];
}

// ---- pass C: scatter packed edges into bin-contiguous regions ----
__global__ __launch_bounds__(256) void k_scatbin(const int* __restrict__ row,
                                                 const int* __restrict__ col,
                                                 const int* __restrict__ H,
                                                 const int* __restrict__ binstart,
                                                 unsigned* __restrict__ binned,
                                                 int E, int NB, int CE) {
    __shared__ int off[MAXNB];
    int eb = blockIdx.x, t = threadIdx.x;
    for (int i = t; i < NB; i += 256) off[i] = binstart[i] + H[eb * NB + i];
    __syncthreads();
    int e0 = eb * CE, e1 = min(E, e0 + CE);
    for (int e = e0 + t; e < e1; e += 256) {
        int c = col[e], r = row[e];
        int slot = atomicAdd(&off[c >> 8], 1);
        binned[slot] = ((unsigned)(c & 255) << 24) | (unsigned)r;
    }
}

// ---- pass D: per-bin CSR finalize in LDS ----
__global__ __launch_bounds__(256) void k_bincsr(const unsigned* __restrict__ binned,
                                                const int* __restrict__ binstart,
                                                const int* __restrict__ nt,
                                                int* __restrict__ srcidx,
                                                int* __restrict__ rowptr,
                                                float* __restrict__ dinv,
                                                int2* __restrict__ pk, int N, int NB) {
    __shared__ unsigned arr[EBIN_CAP];
    __shared__ int sorted_[EBIN_CAP];
    __shared__ int cnt[BINW];
    __shared__ int base[BINW];
    __shared__ int cursor[BINW];
    int b = blockIdx.x, t = threadIdx.x;
    int s0 = binstart[b], s1 = binstart[b + 1];
    int binsz = s1 - s0;
    if (binsz > EBIN_CAP) binsz = EBIN_CAP;
    cnt[t] = 0;
    for (int i = t; i < binsz; i += 256) arr[i] = binned[s0 + i];
    __syncthreads();
    for (int i = t; i < binsz; i += 256) atomicAdd(&cnt[arr[i] >> 24], 1);
    __syncthreads();
    int v = cnt[t];
    base[t] = v;
    __syncthreads();
    for (int off = 1; off < 256; off <<= 1) {
        int tv = (t >= off) ? base[t - off] : 0;
        __syncthreads();
        base[t] += tv;
        __syncthreads();
    }
    int excl = base[t] - v;
    __syncthreads();
    base[t] = excl;
    cursor[t] = excl;
    __syncthreads();
    for (int i = t; i < binsz; i += 256) {
        unsigned val = arr[i];
        int pos = atomicAdd(&cursor[val >> 24], 1);
        sorted_[pos] = (int)(val & 0xFFFFFF);
    }
    __syncthreads();
    for (int i = t; i < binsz; i += 256) srcidx[s0 + i] = sorted_[i];
    int node = b * BINW + t;
    if (node < N) {
        rowptr[node] = s0 + base[t];
        float di = rsqrtf((float)cnt[t] + 1.0f);   // +1 = self loop
        dinv[node] = di;
        pk[node] = make_int2(nt[node], __float_as_int(di));
    }
    if (b == NB - 1 && t == 0) rowptr[N] = s1;
}

// ---- per-edge packed operand in CSR order ----
__global__ void k_buildepk(const int* __restrict__ srcidx, const int2* __restrict__ pk,
                           unsigned* __restrict__ epku, int E) {
    int i = blockIdx.x * blockDim.x + threadIdx.x;
    if (i >= E) return;
    int2 p = pk[srcidx[i]];
    epku[i] = ((unsigned)p.x << 16) |
              (unsigned)__half_as_ushort(__float2half(__int_as_float(p.y)));
}

// ---- embW1 = emb_table @ W1 ----
__global__ void k_embW1(const float* __restrict__ emb, const float* __restrict__ W1,
                        float* __restrict__ embW1, int V) {
    __shared__ float er[DD];
    int v = blockIdx.x, j = threadIdx.x;
    er[j] = emb[v * DD + j];
    __syncthreads();
    float acc = 0.0f;
    #pragma unroll
    for (int d = 0; d < DD; ++d) acc += er[d] * W1[d * DD + j];
    embW1[v * DD + j] = acc;
}

// ---- pack W (64x64 f32) into half2 pairs: Wpk[p*64+j] = {W[2p][j], W[2p+1][j]} ----
__global__ void k_packW(const float* __restrict__ W, unsigned* __restrict__ Wpk) {
    int t = blockIdx.x * blockDim.x + threadIdx.x;
    if (t >= 32 * DD) return;
    int p = t >> 6, j = t & 63;
    __half2 h = __floats2half2_rn(W[(2 * p) * DD + j], W[(2 * p + 1) * DD + j]);
    Wpk[t] = __builtin_bit_cast(unsigned, h);
}

// epilogue dot for t distributed 4 features/lane (lanes 0-15): pair p in lane p>>1
__device__ __forceinline__ float epi_dot_q(float4 v, const unsigned* Wc) {
    __half2 h0 = __floats2half2_rn(v.x, v.y);
    __half2 h1 = __floats2half2_rn(v.z, v.w);
    int vp0 = __builtin_bit_cast(int, h0);
    int vp1 = __builtin_bit_cast(int, h1);
    float o0 = 0.f, o1 = 0.f, o2 = 0.f, o3 = 0.f;
    #pragma unroll
    for (int p = 0; p < 32; p += 4) {
        o0 = fdot2u((unsigned)__builtin_amdgcn_readlane(vp0, (p + 0) >> 1), Wc[p + 0], o0);
        o1 = fdot2u((unsigned)__builtin_amdgcn_readlane(vp1, (p + 1) >> 1), Wc[p + 1], o1);
        o2 = fdot2u((unsigned)__builtin_amdgcn_readlane(vp0, (p + 2) >> 1), Wc[p + 2], o2);
        o3 = fdot2u((unsigned)__builtin_amdgcn_readlane(vp1, (p + 3) >> 1), Wc[p + 3], o3);
    }
    return (o0 + o1) + (o2 + o3);
}

__device__ __forceinline__ void acc_h4(float4& a, uint2 r) {
    float2 f0 = __half22float2(*(const __half2*)&r.x);
    float2 f1 = __half22float2(*(const __half2*)&r.y);
    a.x += f0.x; a.y += f0.y; a.z += f1.x; a.w += f1.y;
}

// quarter-wave gather, 2-stage software pipeline
__device__ __forceinline__ float4 gather_sum_q(const int* __restrict__ srcidx,
                                               const __half* __restrict__ Hs,
                                               int s, int e, int g, int l) {
    float4 A = {0,0,0,0}, B = {0,0,0,0}, C = {0,0,0,0}, D = {0,0,0,0};
    int k = s;
    int kend = s + ((e - s) & ~15);
    if (k < kend) {
        uint2 r0 = *(const uint2*)(Hs + (long)srcidx[k + g] * DD + 4 * l);
        uint2 r1 = *(const uint2*)(Hs + (long)srcidx[k + 4 + g] * DD + 4 * l);
        uint2 r2 = *(const uint2*)(Hs + (long)srcidx[k + 8 + g] * DD + 4 * l);
        uint2 r3 = *(const uint2*)(Hs + (long)srcidx[k + 12 + g] * DD + 4 * l);
        k += 16;
        for (; k < kend; k += 16) {
            uint2 n0 = *(const uint2*)(Hs + (long)srcidx[k + g] * DD + 4 * l);
            uint2 n1 = *(const uint2*)(Hs + (long)srcidx[k + 4 + g] * DD + 4 * l);
            uint2 n2 = *(const uint2*)(Hs + (long)srcidx[k + 8 + g] * DD + 4 * l);
            uint2 n3 = *(const uint2*)(Hs + (long)srcidx[k + 12 + g] * DD + 4 * l);
            acc_h4(A, r0); acc_h4(B, r1); acc_h4(C, r2); acc_h4(D, r3);
            r0 = n0; r1 = n1; r2 = n2; r3 = n3;
        }
        acc_h4(A, r0); acc_h4(B, r1); acc_h4(C, r2); acc_h4(D, r3);
    }
    for (; k < e; k += 4) {
        if (k + g < e) {
            uint2 rr = *(const uint2*)(Hs + (long)srcidx[k + g] * DD + 4 * l);
            acc_h4(A, rr);
        }
    }
    A.x += B.x + C.x + D.x; A.y += B.y + C.y + D.y;
    A.z += B.z + C.z + D.z; A.w += B.w + C.w + D.w;
    A.x += __shfl_xor(A.x, 16, 64); A.x += __shfl_xor(A.x, 32, 64);
    A.y += __shfl_xor(A.y, 16, 64); A.y += __shfl_xor(A.y, 32, 64);
    A.z += __shfl_xor(A.z, 16, 64); A.z += __shfl_xor(A.z, 32, 64);
    A.w += __shfl_xor(A.w, 16, 64); A.w += __shfl_xor(A.w, 32, 64);
    return A;
}

// ---- layer-1, quarter-wave (LDS ew table; no matmul) ----
__global__ __launch_bounds__(256, 4) void k_agg1_fused(const int* __restrict__ rowptr,
                                                    const unsigned* __restrict__ epku,
                                                    const int2* __restrict__ pk,
                                                    const float* __restrict__ embW1,
                                                    const float* __restrict__ b1,
                                                    __half* __restrict__ OUT, int N, int V) {
    __shared__ float ew[30 * DD];
    int tid = threadIdx.x;
    for (int k = tid; k < V * DD; k += 256) ew[k] = embW1[k];
    __syncthreads();
    int lane = tid & 63;
    int g = lane >> 4, l = lane & 15;
    float4 bq = *(const float4*)(b1 + 4 * l);
    int wave0 = blockIdx.x * 4 + (tid >> 6);
    int wstride = gridDim.x * 4;
    for (int node = __builtin_amdgcn_readfirstlane(wave0); node < N;
         node += wstride) {
        int s = rowptr[node], e = rowptr[node + 1];
        float4 acc = {0.f, 0.f, 0.f, 0.f};
        int k = s;
        for (; k + 8 <= e; k += 8) {
            unsigned u0 = epku[k + g];
            unsigned u1 = epku[k + 4 + g];
            int t0 = u0 >> 16, t1 = u1 >> 16;
            float d0 = __half2float(__ushort_as_half((unsigned short)(u0 & 0xFFFF)));
            float d1 = __half2float(__ushort_as_half((unsigned short)(u1 & 0xFFFF)));
            float4 w0 = *(const float4*)(ew + t0 * DD + 4 * l);
            float4 w1 = *(const float4*)(ew + t1 * DD + 4 * l);
            acc.x += w0.x * d0 + w1.x * d1;
            acc.y += w0.y * d0 + w1.y * d1;
            acc.z += w0.z * d0 + w1.z * d1;
            acc.w += w0.w * d0 + w1.w * d1;
        }
        if (k + 4 <= e) {
            unsigned u0 = epku[k + g];
            int t0 = u0 >> 16;
            float d0 = __half2float(__ushort_as_half((unsigned short)(u0 & 0xFFFF)));
            float4 w0 = *(const float4*)(ew + t0 * DD + 4 * l);
            acc.x += w0.x * d0; acc.y += w0.y * d0;
            acc.z += w0.z * d0; acc.w += w0.w * d0;
            k += 4;
        }
        if (k + g < e) {
            unsigned u0 = epku[k + g];
            int t0 = u0 >> 16;
            float d0 = __half2float(__ushort_as_half((unsigned short)(u0 & 0xFFFF)));
            float4 w0 = *(const float4*)(ew + t0 * DD + 4 * l);
            acc.x += w0.x * d0; acc.y += w0.y * d0;
            acc.z += w0.z * d0; acc.w += w0.w * d0;
        }
        acc.x += __shfl_xor(acc.x, 16, 64); acc.x += __shfl_xor(acc.x, 32, 64);
        acc.y += __shfl_xor(acc.y, 16, 64); acc.y += __shfl_xor(acc.y, 32, 64);
        acc.z += __shfl_xor(acc.z, 16, 64); acc.z += __shfl_xor(acc.z, 32, 64);
        acc.w += __shfl_xor(acc.w, 16, 64); acc.w += __shfl_xor(acc.w, 32, 64);
        int2 pc = pk[node];
        float dc = __int_as_float(pc.y);
        float4 wc = *(const float4*)(ew + pc.x * DD + 4 * l);
        float4 v;
        v.x = fmaxf((acc.x + wc.x * dc) * dc + bq.x, 0.f) * dc;
        v.y = fmaxf((acc.y + wc.y * dc) * dc + bq.y, 0.f) * dc;
        v.z = fmaxf((acc.z + wc.z * dc) * dc + bq.z, 0.f) * dc;
        v.w = fmaxf((acc.w + wc.w * dc) * dc + bq.w, 0.f) * dc;
        if (g == 0) {
            __half2 h0 = __floats2half2_rn(v.x, v.y);
            __half2 h1 = __floats2half2_rn(v.z, v.w);
            uint2 st;
            st.x = __builtin_bit_cast(unsigned, h0);
            st.y = __builtin_bit_cast(unsigned, h1);
            *(uint2*)(OUT + (long)node * DD + 4 * l) = st;
        }
    }
}

// ---- layer-2: gather v1s; t=(Σ+self)*dc; v2=relu(t@W2 + b2); OUT=fp16(v2*dc) ----
__global__ __launch_bounds__(256, 4) void k_agg2_fused(const int* __restrict__ rowptr,
                                                    const int* __restrict__ srcidx,
                                                    const float* __restrict__ dinv,
                                                    const __half* __restrict__ Hs,
                                                    const float* __restrict__ b2,
                                                    const unsigned* __restrict__ W2pk,
                                                    __half* __restrict__ OUT, int N) {
    int tid = threadIdx.x;
    int lane = tid & 63;
    int g = lane >> 4, l = lane & 15;
    unsigned Wc[32];
    #pragma unroll
    for (int p = 0; p < 32; ++p) Wc[p] = W2pk[p * DD + lane];
    float bl = b2[lane];
    int wave0 = blockIdx.x * 4 + (tid >> 6);
    int wstride = gridDim.x * 4;
    for (int node = __builtin_amdgcn_readfirstlane(wave0); node < N;
         node += wstride) {
        int s = rowptr[node], e = rowptr[node + 1];
        float4 acc = gather_sum_q(srcidx, Hs, s, e, g, l);
        float dc = dinv[node];
        uint2 sr = *(const uint2*)(Hs + (long)node * DD + 4 * l);
        float2 s0 = __half22float2(*(const __half2*)&sr.x);
        float2 s1 = __half22float2(*(const __half2*)&sr.y);
        float4 t;
        t.x = (acc.x + s0.x) * dc;
        t.y = (acc.y + s0.y) * dc;
        t.z = (acc.z + s1.x) * dc;
        t.w = (acc.w + s1.y) * dc;
        float u = epi_dot_q(t, Wc);
        float v2 = fmaxf(u + bl, 0.f);
        OUT[(long)node * DD + lane] = __float2half(v2 * dc);
    }
}

// ---- layer-3 + pooling in v2-space: y = dc*(Σ v2s + self); pool[batch] += y. ----
__global__ __launch_bounds__(256, 4) void k_agg3_pool(const int* __restrict__ rowptr,
                                                   const int* __restrict__ srcidx,
                                                   const float* __restrict__ dinv,
                                                   const __half* __restrict__ Hs,
                                                   const int* __restrict__ batch,
                                                   float* __restrict__ pool,
                                                   int N, int chunk) {
    int tid = threadIdx.x;
    int lane = tid & 63;
    int g = lane >> 4, l = lane & 15;
    int w = __builtin_amdgcn_readfirstlane(blockIdx.x * 4 + (tid >> 6));
    int start = w * chunk;
    if (start >= N) return;
    int endn = min(N, start + chunk);
    int gcur = batch[start];
    float4 pacc = {0.f, 0.f, 0.f, 0.f};
    for (int node = start; node < endn; ++node) {
        int s = rowptr[node], e = rowptr[node + 1];
        float4 acc = gather_sum_q(srcidx, Hs, s, e, g, l);
        float dc = dinv[node];
        uint2 sr = *(const uint2*)(Hs + (long)node * DD + 4 * l);
        float2 s0 = __half22float2(*(const __half2*)&sr.x);
        float2 s1 = __half22float2(*(const __half2*)&sr.y);
        float4 v;
        v.x = (acc.x + s0.x) * dc;
        v.y = (acc.y + s0.y) * dc;
        v.z = (acc.z + s1.x) * dc;
        v.w = (acc.w + s1.y) * dc;
        int gb = batch[node];
        if (gb != gcur) {
            if (g == 0) {
                atomicAdd(&pool[gcur * DD + 4 * l + 0], pacc.x);
                atomicAdd(&pool[gcur * DD + 4 * l + 1], pacc.y);
                atomicAdd(&pool[gcur * DD + 4 * l + 2], pacc.z);
                atomicAdd(&pool[gcur * DD + 4 * l + 3], pacc.w);
            }
            gcur = gb;
            pacc = v;
        } else {
            pacc.x += v.x; pacc.y += v.y; pacc.z += v.z; pacc.w += v.w;
        }
    }
    if (g == 0) {
        atomicAdd(&pool[gcur * DD + 4 * l + 0], pacc.x);
        atomicAdd(&pool[gcur * DD + 4 * l + 1], pacc.y);
        atomicAdd(&pool[gcur * DD + 4 * l + 2], pacc.z);
        atomicAdd(&pool[gcur * DD + 4 * l + 3], pacc.w);
    }
}

// ---- final: per-graph W3 matmul (f32) + b3, mean, L2 normalize ----
__global__ void k_final(const float* __restrict__ pool, const int* __restrict__ batch,
                        const float* __restrict__ W3, const float* __restrict__ b3,
                        float* __restrict__ out, int N) {
    __shared__ float pr[DD];
    int g = blockIdx.x, j = threadIdx.x;
    pr[j] = pool[g * DD + j];
    __syncthreads();
    int lo = 0, hi = N;
    while (lo < hi) { int m = (lo + hi) >> 1; if (batch[m] < g) lo = m + 1; else hi = m; }
    int lo2 = lo; hi = N;
    while (lo2 < hi) { int m = (lo2 + hi) >> 1; if (batch[m] < g + 1) lo2 = m + 1; else hi = m; }
    float cnt = fmaxf((float)(lo2 - lo), 1.0f);
    float acc = 0.0f;
    #pragma unroll
    for (int d = 0; d < DD; ++d) acc += pr[d] * W3[d * DD + j];
    float v = acc / cnt + b3[j];
    float sq = v * v;
    #pragma unroll
    for (int off = 32; off > 0; off >>= 1) sq += __shfl_down(sq, off, 64);
    float nrm = __shfl(sq, 0, 64);
    out[g * DD + j] = v / sqrtf(nrm);
}

extern "C" void kernel_launch(void* const* d_in, const int* in_sizes, int n_in,
                              void* d_out, int out_size, void* d_ws, size_t ws_size,
                              hipStream_t stream) {
    const int*   node_types = (const int*)d_in[0];
    const int*   edge_index = (const int*)d_in[1];
    const int*   batch      = (const int*)d_in[2];
    const float* emb        = (const float*)d_in[3];
    const float* W1 = (const float*)d_in[4];
    const float* b1 = (const float*)d_in[5];
    const float* W2 = (const float*)d_in[6];
    const float* b2 = (const float*)d_in[7];
    const float* W3 = (const float*)d_in[8];
    const float* b3 = (const float*)d_in[9];
    const int N = in_sizes[0];
    const int E = in_sizes[1] / 2;
    const int V = in_sizes[3] / DD;
    const int* row = edge_index;
    const int* col = edge_index + E;
    const long ND = (long)N * DD;
    const int NB = (N + BINW - 1) / BINW;
    const int CE = (E + EB - 1) / EB;

    // workspace layout
    char* p = (char*)d_ws;
    __half*   hsA      = (__half*)p;      p += ND * sizeof(__half);
    __half*   hsB      = (__half*)p;      p += ND * sizeof(__half);
    int*      srcidx   = (int*)p;         p += (size_t)E * sizeof(int);
    unsigned* epku     = (unsigned*)p;    p += (size_t)E * sizeof(unsigned);
    unsigned* binned   = (unsigned*)p;    p += (size_t)E * sizeof(unsigned);
    int*      H        = (int*)p;         p += (size_t)EB * NB * sizeof(int);
    int*      bintot   = (int*)p;         p += (size_t)(NB + 4) * sizeof(int);
    int*      binstart = (int*)p;         p += (size_t)(NB + 4) * sizeof(int);
    float*    dinv     = (float*)p;       p += (size_t)N * sizeof(float);
    int2*     pk       = (int2*)p;        p += (size_t)N * sizeof(int2);
    int*      rowptr   = (int*)p;         p += (size_t)(N + 4) * sizeof(int);
    float*    pool     = (float*)p;       p += (size_t)NUM_GRAPHS * DD * sizeof(float);
    float*    embW1    = (float*)p;       p += (size_t)V * DD * sizeof(float);
    unsigned* W2pk     = (unsigned*)p;    p += 32 * DD * sizeof(unsigned);

    // ---- atomic-free sort-based CSR build ----
    k_hist<<<EB, 256, 0, stream>>>(col, H, E, NB, CE);
    k_scanA<<<NB, 256, 0, stream>>>(H, bintot, NB);
    k_scanB<<<1, 512, 0, stream>>>(bintot, binstart, NB);
    k_scatbin<<<EB, 256, 0, stream>>>(row, col, H, binstart, binned, E, NB, CE);
    k_bincsr<<<NB, 256, 0, stream>>>(binned, binstart, node_types, srcidx, rowptr,
                                     dinv, pk, N, NB);
    k_buildepk<<<(E + 255) / 256, 256, 0, stream>>>(srcidx, pk, epku, E);

    // ---- weight prep ----
    k_embW1<<<V, DD, 0, stream>>>(emb, W1, embW1, V);
    k_packW<<<8, 256, 0, stream>>>(W2, W2pk);

    // ---- layer 1 -> v1s fp16 (quarter-wave, no matmul) ----
    k_agg1_fused<<<AGG_BLOCKS, 256, 0, stream>>>(rowptr, epku, pk, embW1, b1,
                                                 hsA, N, V);
    // ---- layer 2: gather + W2 post-agg -> v2s fp16 ----
    k_agg2_fused<<<AGG_BLOCKS, 256, 0, stream>>>(rowptr, srcidx, dinv, hsA, b2, W2pk,
                                                 hsB, N);
    // ---- layer 3 + pooling in v2-space ----
    hipMemsetAsync(pool, 0, (size_t)(NUM_GRAPHS * DD) * sizeof(float), stream);
    const int totalWaves = AGG_BLOCKS * 4;
    const int chunk = (N + totalWaves - 1) / totalWaves;
    k_agg3_pool<<<AGG_BLOCKS, 256, 0, stream>>>(rowptr, srcidx, dinv, hsB, batch,
                                                pool, N, chunk);
    // ---- per-graph W3 + b3 + mean + normalize ----
    k_final<<<NUM_GRAPHS, DD, 0, stream>>>(pool, batch, W3, b3, (float*)d_out, N);
}